// Round 11
// baseline (126.311 us; speedup 1.0000x reference)
//
#include <hip/hip_runtime.h>

// LightGCN layer: out[d] = in_deg[d]^-1/2 * sum_{e:dst[e]=d} x[src[e]] * out_deg[src[e]]^-1/2
//
// Round 23: base = R22 (best, 120.6). One lever: partition occupancy.
//  The R20 bucketed partition is LDS-op/barrier-heavy (hist atomics, scan,
//  place atomics) = latency-bound, but ran 1 block/CU (37 KB LDS, 224
//  blocks). EPB 3584->1792 halves per-block LDS to ~27 KB (16 KB scan
//  arrays + 10.7 KB buffers) -> 2 blocks/CU co-resident (2048 thr = CU
//  cap, 8 waves/SIMD), 447 blocks. Same lever that won R14/R15/R19.
//  Costs: aggregate scan 2x (~+1 us), writeout runs 9->4.6 entries (stores
//  cheap per R20). Everything else unchanged from R22.
//  Pre-commit: if gain < 2 us, declare roofline next round
//  (fill 46 + gather 44 floor + staging ~20 + gaps ~7 ~= 117 achievable).

#define D_FEAT 96
#define CAP 64
#define PART_SHIFT 7
#define PNODES 128          // nodes per partition (1 << PART_SHIFT)
#define NP_MAX 512
#define EPB 1792            // 800k edges -> 447 blocks, 2 blocks/CU
#define EREG 4
#define VTHREADS 448        // EPB / 4: threads doing vectorized load/place
#define PTHREADS 1024
#define OVF_CAP 8192

__device__ __forceinline__ unsigned short f2bf_rne(float f) {
    unsigned u = __float_as_uint(f);
    unsigned r = (u >> 16) & 1u;
    u += 0x7fffu + r;
    return (unsigned short)(u >> 16);
}

// ------ pass 1: dual-side multisplit partition, LDS-bucketed writeout ------

__global__ __launch_bounds__(PTHREADS) void partition_kernel(
        const int* __restrict__ src, const int* __restrict__ dst,
        int n_edges, int np, int stride,
        int* __restrict__ pcur_d, int* __restrict__ pcur_s,
        unsigned* __restrict__ pbuf_d, unsigned short* __restrict__ pbuf_s,
        int* __restrict__ ctr,            // [0]=ovf_n [1]=povf_n [2]=sovf_n
        int* __restrict__ povf_d, int* __restrict__ sovf_d) {
    __shared__ int hist[2 * NP_MAX];          // [0,512): dst  [512,1024): src
    __shared__ int sdx[2 * NP_MAX];           // exclusive scan (src 0-based)
    __shared__ int ocur[2 * NP_MAX];          // placement counters
    __shared__ int gbase[2 * NP_MAX];         // reserved global bases
    __shared__ unsigned bufd[EPB];            // 7168 B: dst-side packed edges
    __shared__ unsigned short bufs[EPB];      // 3584 B: src-side ids
    const int t = threadIdx.x;
    const int base = blockIdx.x * EPB;
    const int eend = min(n_edges, base + EPB);
    const int nval = eend - base;
    const bool full = (base + EPB <= n_edges);

    hist[t] = 0; ocur[t] = 0;
    __syncthreads();

    unsigned v[EREG];
    if (full) {
        // vectorized: threads t < 448 handle edges base+4t .. base+4t+3
        if (t < VTHREADS) {
            const int4 s4 = *(const int4*)(src + base + (t << 2));
            const int4 d4 = *(const int4*)(dst + base + (t << 2));
            v[0] = (unsigned)d4.x | ((unsigned)s4.x << 16);
            v[1] = (unsigned)d4.y | ((unsigned)s4.y << 16);
            v[2] = (unsigned)d4.z | ((unsigned)s4.z << 16);
            v[3] = (unsigned)d4.w | ((unsigned)s4.w << 16);
            #pragma unroll
            for (int k = 0; k < EREG; ++k) {
                atomicAdd(&hist[(v[k] & 0xffffu) >> PART_SHIFT], 1);
                atomicAdd(&hist[NP_MAX + (v[k] >> (16 + PART_SHIFT))], 1);
            }
        }
    } else {
        #pragma unroll
        for (int k = 0; k < EREG; ++k) {
            int i = base + t + (k << 10);
            if (i < eend) {
                int s = src[i], d = dst[i];
                unsigned pv = (unsigned)d | ((unsigned)s << 16);
                v[k] = pv;
                atomicAdd(&hist[d >> PART_SHIFT], 1);
                atomicAdd(&hist[NP_MAX + (s >> PART_SHIFT)], 1);
            }
        }
    }
    __syncthreads();

    // inclusive Hillis-Steele scan over the 1024-entry concat histogram
    sdx[t] = hist[t];
    __syncthreads();
    for (int off = 1; off < 2 * NP_MAX; off <<= 1) {
        int a = sdx[t];
        int b = (t >= off) ? sdx[t - off] : 0;
        __syncthreads();
        sdx[t] = a + b;
        __syncthreads();
    }
    // convert to exclusive; re-base src half to 0
    {
        int incl = sdx[t];
        int td = sdx[NP_MAX - 1];           // total dst entries (= nval)
        __syncthreads();
        sdx[t] = incl - hist[t] - (t >= NP_MAX ? td : 0);
        __syncthreads();
    }

    // reserve global ranges (one atomic per non-empty (block, partition))
    {
        int c = hist[t];
        if (t < NP_MAX) gbase[t] = c ? atomicAdd(&pcur_d[t], c) : 0;
        else            gbase[t] = c ? atomicAdd(&pcur_s[t - NP_MAX], c) : 0;
    }

    // place edges into LDS buckets
    if (full) {
        if (t < VTHREADS) {
            #pragma unroll
            for (int k = 0; k < EREG; ++k) {
                unsigned pv = v[k];
                int pd = (int)((pv & 0xffffu) >> PART_SHIFT);
                int sl = sdx[pd] + atomicAdd(&ocur[pd], 1);
                bufd[sl] = pv;
                int ps = (int)(pv >> (16 + PART_SHIFT));
                int sl2 = sdx[NP_MAX + ps] + atomicAdd(&ocur[NP_MAX + ps], 1);
                bufs[sl2] = (unsigned short)(pv >> 16);
            }
        }
    } else {
        #pragma unroll
        for (int k = 0; k < EREG; ++k) {
            int i = base + t + (k << 10);
            if (i < eend) {
                unsigned pv = v[k];
                int pd = (int)((pv & 0xffffu) >> PART_SHIFT);
                int sl = sdx[pd] + atomicAdd(&ocur[pd], 1);
                bufd[sl] = pv;
                int ps = (int)(pv >> (16 + PART_SHIFT));
                int sl2 = sdx[NP_MAX + ps] + atomicAdd(&ocur[NP_MAX + ps], 1);
                bufs[sl2] = (unsigned short)(pv >> 16);
            }
        }
    }
    __syncthreads();

    // linear writeout: consecutive slots -> consecutive global addresses
    for (int i = t; i < nval; i += PTHREADS) {
        unsigned pv = bufd[i];
        int p = (int)((pv & 0xffffu) >> PART_SHIFT);
        int j = gbase[p] + (i - sdx[p]);
        if (j < stride) pbuf_d[(size_t)p * stride + j] = pv;
        else { int k2 = atomicAdd(&ctr[1], 1); if (k2 < OVF_CAP) povf_d[k2] = (int)pv; }
    }
    for (int i = t; i < nval; i += PTHREADS) {
        int s = (int)bufs[i];
        int p = s >> PART_SHIFT;
        int j = gbase[NP_MAX + p] + (i - sdx[NP_MAX + p]);
        if (j < stride) pbuf_s[(size_t)p * stride + j] = (unsigned short)s;
        else { int k3 = atomicAdd(&ctr[2], 1); if (k3 < OVF_CAP) sovf_d[k3] = s; }
    }
}

// ---- pass 2: bin dst + count src + integrate povf/sovf + convert (fused) ----

__global__ __launch_bounds__(PTHREADS) void bincnt_kernel(
        const unsigned* __restrict__ pbuf_d, const int* __restrict__ pcur_d,
        const unsigned short* __restrict__ pbuf_s, const int* __restrict__ pcur_s,
        int stride, int n_nodes,
        const float* __restrict__ x, unsigned* __restrict__ xs,
        int* __restrict__ cursor, int* __restrict__ out_cnt,
        unsigned short* __restrict__ slots,
        int* __restrict__ ctr,
        const int* __restrict__ povf_d, const int* __restrict__ sovf_d,
        int* __restrict__ ovf_d) {
    __shared__ unsigned short lslots[PNODES * CAP];   // 16 KB
    __shared__ int lcnt[PNODES];
    __shared__ int lout[PNODES];
    const int b = blockIdx.x;
    const int nbase = b << PART_SHIFT;
    const int nloc = min(PNODES, n_nodes - nbase);

    for (int i = threadIdx.x; i < PNODES; i += PTHREADS) { lcnt[i] = 0; lout[i] = 0; }
    __syncthreads();

    // dst side: bin into slots
    int n = pcur_d[b]; if (n > stride) n = stride;
    for (int i = threadIdx.x; i < n; i += PTHREADS) {
        unsigned pv = pbuf_d[(size_t)b * stride + i];
        int dl = (int)(pv & (unsigned)(PNODES - 1));   // d - nbase (aligned)
        int s  = (int)(pv >> 16);
        int pos = atomicAdd(&lcnt[dl], 1);
        if (pos < CAP) lslots[dl * CAP + pos] = (unsigned short)s;
        else { int k = atomicAdd(&ctr[0], 1); if (k < OVF_CAP) ovf_d[k] = (int)pv; }
    }
    // src side: histogram out-degree
    int n2 = pcur_s[b]; if (n2 > stride) n2 = stride;
    for (int i = threadIdx.x; i < n2; i += PTHREADS) {
        int s = (int)pbuf_s[(size_t)b * stride + i];
        atomicAdd(&lout[s & (PNODES - 1)], 1);
    }
    // integrate partition-buffer overflow entries for THIS node range
    // (ctr[1]/ctr[2] are normally 0 -> these loops never run)
    int npv = ctr[1];
    if (npv > 0) {
        if (npv > OVF_CAP) npv = OVF_CAP;
        for (int i = threadIdx.x; i < npv; i += PTHREADS) {
            unsigned pv = (unsigned)povf_d[i];
            int d = (int)(pv & 0xffffu);
            if ((d >> PART_SHIFT) == b) {
                int dl = d & (PNODES - 1);
                int pos = atomicAdd(&lcnt[dl], 1);
                if (pos < CAP) lslots[dl * CAP + pos] = (unsigned short)(pv >> 16);
                else { int k = atomicAdd(&ctr[0], 1); if (k < OVF_CAP) ovf_d[k] = (int)pv; }
            }
        }
    }
    int nsv = ctr[2];
    if (nsv > 0) {
        if (nsv > OVF_CAP) nsv = OVF_CAP;
        for (int i = threadIdx.x; i < nsv; i += PTHREADS) {
            int s = sovf_d[i];
            if ((s >> PART_SHIFT) == b) atomicAdd(&lout[s & (PNODES - 1)], 1);
        }
    }
    __syncthreads();

    for (int i = threadIdx.x; i < nloc; i += PTHREADS) {
        cursor[nbase + i]  = lcnt[i];
        out_cnt[nbase + i] = lout[i];
    }
    // slot tile write-out (coalesced)
    const unsigned* ls = (const unsigned*)lslots;
    unsigned* gs = (unsigned*)slots + (size_t)nbase * (CAP / 2);
    const int ncopy = nloc * (CAP / 2);
    for (int i = threadIdx.x; i < ncopy; i += PTHREADS) gs[i] = ls[i];

    // convert this block's x rows -> pre-scaled bf16 xs (float4 granular)
    const int ntot = nloc * 24;                 // 24 float4 per 96-feat row
    for (int i = threadIdx.x; i < ntot; i += PTHREADS) {
        int nd = i / 24;
        int j  = i - nd * 24;
        int c  = lout[nd];
        float w = rsqrtf((float)(c < 1 ? 1 : c));
        float4 vv = ((const float4*)(x + (size_t)(nbase + nd) * D_FEAT))[j];
        unsigned lo0 = f2bf_rne(vv.x * w), hi0 = f2bf_rne(vv.y * w);
        unsigned lo1 = f2bf_rne(vv.z * w), hi1 = f2bf_rne(vv.w * w);
        uint2 o;
        o.x = lo0 | (hi0 << 16);
        o.y = lo1 | (hi1 << 16);
        ((uint2*)(xs + (size_t)(nbase + nd) * 48))[j] = o;
    }
}

// ---------------- gather: wave per node, 16-deep unrolled, self-serve ovf ----

__global__ __launch_bounds__(256) void gather_kernel(
        const unsigned* __restrict__ xs,
        const unsigned short* __restrict__ slots,
        const int* __restrict__ cursor,
        const float* __restrict__ x,
        const int* __restrict__ out_cnt,
        const int* __restrict__ ctr,
        const int* __restrict__ ovf_d,
        float* __restrict__ out, int n_nodes) {
    int wid  = threadIdx.x >> 6;
    int lane = threadIdx.x & 63;
    int node = __builtin_amdgcn_readfirstlane(blockIdx.x * 4 + wid);
    if (node >= n_nodes) return;

    int cnt_all = __builtin_amdgcn_readfirstlane(cursor[node]);
    int cnt = cnt_all < CAP ? cnt_all : CAP;

    float accx = 0.f, accy = 0.f;
    const bool act = lane < 48;        // 48 lanes x (2 bf16) = 96 features

    if (cnt > 0) {
        int idx  = lane < cnt ? lane : cnt - 1;
        int sval = (int)slots[node * CAP + idx];   // lane l holds slot l's src id

        int e = 0;
        for (; e + 16 <= cnt; e += 16) {
            if (act) {
                unsigned u[16];
                #pragma unroll
                for (int k = 0; k < 16; ++k) {
                    int s = __builtin_amdgcn_readlane(sval, e + k);
                    u[k] = xs[s * 48 + lane];
                }
                #pragma unroll
                for (int k = 0; k < 16; ++k) {
                    accx += __uint_as_float(u[k] << 16);
                    accy += __uint_as_float(u[k] & 0xffff0000u);
                }
            }
        }
        for (; e + 4 <= cnt; e += 4) {
            if (act) {
                unsigned u[4];
                #pragma unroll
                for (int k = 0; k < 4; ++k) {
                    int s = __builtin_amdgcn_readlane(sval, e + k);
                    u[k] = xs[s * 48 + lane];
                }
                #pragma unroll
                for (int k = 0; k < 4; ++k) {
                    accx += __uint_as_float(u[k] << 16);
                    accy += __uint_as_float(u[k] & 0xffff0000u);
                }
            }
        }
        for (; e < cnt; ++e) {
            if (act) {
                int s = __builtin_amdgcn_readlane(sval, e);
                unsigned u0 = xs[s * 48 + lane];
                accx += __uint_as_float(u0 << 16);
                accy += __uint_as_float(u0 & 0xffff0000u);
            }
        }
    }

    // self-service overflow: only nodes with in-degree > CAP (normally none).
    if (cnt_all > CAP) {
        int novf = __builtin_amdgcn_readfirstlane(ctr[0]);
        if (novf > OVF_CAP) novf = OVF_CAP;
        for (int k = 0; k < novf; ++k) {
            unsigned pv = (unsigned)ovf_d[k];
            if ((int)(pv & 0xffffu) == node) {
                int s = (int)(pv >> 16);
                int c = out_cnt[s];
                float w = rsqrtf((float)(c < 1 ? 1 : c));
                if (act) {
                    accx += w * x[(size_t)s * D_FEAT + lane * 2];
                    accy += w * x[(size_t)s * D_FEAT + lane * 2 + 1];
                }
            }
        }
    }

    float sc = rsqrtf((float)(cnt_all < 1 ? 1 : cnt_all));
    if (act) {
        float* op = out + (size_t)node * D_FEAT + lane * 2;
        op[0] = accx * sc;
        op[1] = accy * sc;
    }
}

// ---------------- fallback (round-1 atomic scatter, any size) ----------------

__global__ void degree_kernel(const int* __restrict__ src,
                              const int* __restrict__ dst,
                              int* __restrict__ out_cnt,
                              int* __restrict__ in_cnt, int n_edges) {
    int i = blockIdx.x * blockDim.x + threadIdx.x;
    if (i < n_edges) {
        atomicAdd(&out_cnt[src[i]], 1);
        atomicAdd(&in_cnt[dst[i]], 1);
    }
}

__global__ void scale_kernel(float* __restrict__ osc, float* __restrict__ isc, int n) {
    int i = blockIdx.x * blockDim.x + threadIdx.x;
    if (i < n) {
        int c0 = ((const int*)osc)[i];
        int c1 = ((const int*)isc)[i];
        osc[i] = rsqrtf((float)(c0 < 1 ? 1 : c0));
        isc[i] = rsqrtf((float)(c1 < 1 ? 1 : c1));
    }
}

__global__ void scatter_kernel(const float* __restrict__ x,
                               const int* __restrict__ src,
                               const int* __restrict__ dst,
                               const float* __restrict__ osc,
                               const float* __restrict__ isc,
                               float* __restrict__ out, int n_edges) {
    int idx = blockIdx.x * blockDim.x + threadIdx.x;
    int e = idx / 24, c = idx % 24;
    if (e >= n_edges) return;
    int s = src[e], d = dst[e];
    float w = osc[s] * isc[d];
    const float4 v = *(const float4*)(x + (size_t)s * D_FEAT + c * 4);
    float* o = out + (size_t)d * D_FEAT + c * 4;
    unsafeAtomicAdd(o + 0, v.x * w);
    unsafeAtomicAdd(o + 1, v.y * w);
    unsafeAtomicAdd(o + 2, v.z * w);
    unsafeAtomicAdd(o + 3, v.w * w);
}

// ---------------- launcher ----------------

extern "C" void kernel_launch(void* const* d_in, const int* in_sizes, int n_in,
                              void* d_out, int out_size, void* d_ws, size_t ws_size,
                              hipStream_t stream) {
    const float* x  = (const float*)d_in[0];
    const int* src  = (const int*)d_in[1];
    const int* dst  = (const int*)d_in[2];
    float* out      = (float*)d_out;

    const int n_edges = in_sizes[1];
    const int n_nodes = in_sizes[0] / D_FEAT;

    const int np = (n_nodes + PNODES - 1) / PNODES;
    const int avg = n_edges / (np > 0 ? np : 1);
    const int stride = avg + avg / 4 + 1024;
    const int pblocks = (n_edges + EPB - 1) / EPB;

    const size_t pbuf_words  = (size_t)np * stride;          // dst buffer (uint)
    const size_t pbufs_words = (pbuf_words + 1) / 2;         // src buffer (ushort)

    // ws layout (int32 units). First 2048 ints zeroed each call:
    int* pcur_d  = (int*)d_ws;            // 512
    int* pcur_s  = pcur_d + 512;          // 512
    int* ctr     = pcur_d + 1024;         // 3 (pad to 2048)
    int* ovf_d   = pcur_d + 2048;         // OVF_CAP (packed v)
    int* povf_d  = ovf_d + OVF_CAP;       // OVF_CAP
    int* sovf_d  = povf_d + OVF_CAP;      // OVF_CAP
    int* out_cnt = sovf_d + OVF_CAP;      // 65536
    int* cursor  = out_cnt + 65536;       // 65536
    unsigned* pbuf_dst = (unsigned*)(cursor + 65536);
    unsigned short* pbuf_src = (unsigned short*)(pbuf_dst + pbuf_words);
    unsigned* xs = pbuf_dst + pbuf_words + pbufs_words;
    unsigned short* slots = (unsigned short*)(xs + (size_t)n_nodes * 48);

    const size_t needed = ((size_t)2048 + 3 * OVF_CAP + 2 * 65536 + pbuf_words +
                           pbufs_words + (size_t)n_nodes * 48 +
                           (size_t)n_nodes * (CAP / 2)) * 4;

    if (ws_size >= needed && n_nodes <= 65536 && np <= NP_MAX && pblocks <= 512) {
        // zero pcur_d, pcur_s, ctr
        (void)hipMemsetAsync(d_ws, 0, 2048 * sizeof(int), stream);

        partition_kernel<<<pblocks, PTHREADS, 0, stream>>>(
            src, dst, n_edges, np, stride, pcur_d, pcur_s,
            pbuf_dst, pbuf_src, ctr, povf_d, sovf_d);

        bincnt_kernel<<<np, PTHREADS, 0, stream>>>(
            pbuf_dst, pcur_d, pbuf_src, pcur_s, stride, n_nodes,
            x, xs, cursor, out_cnt, slots, ctr, povf_d, sovf_d, ovf_d);

        gather_kernel<<<(n_nodes + 3) / 4, 256, 0, stream>>>(
            xs, slots, cursor, x, out_cnt, ctr, ovf_d, out, n_nodes);
    } else {
        // fallback: atomic scatter (round-1 path, any size)
        float* osc = (float*)d_ws;
        float* isc = osc + 65536;
        (void)hipMemsetAsync(d_ws, 0, 2 * 65536 * sizeof(int), stream);
        (void)hipMemsetAsync(d_out, 0, (size_t)out_size * sizeof(float), stream);
        degree_kernel<<<(n_edges + 255) / 256, 256, 0, stream>>>(
            src, dst, (int*)osc, (int*)isc, n_edges);
        scale_kernel<<<(n_nodes + 255) / 256, 256, 0, stream>>>(osc, isc, n_nodes);
        const int total = n_edges * 24;
        scatter_kernel<<<(total + 255) / 256, 256, 0, stream>>>(
            x, src, dst, osc, isc, out, n_edges);
    }
}

// Round 12
// 119.634 us; speedup vs baseline: 1.0558x; 1.0558x over previous
//
#include <hip/hip_runtime.h>

// LightGCN layer: out[d] = in_deg[d]^-1/2 * sum_{e:dst[e]=d} x[src[e]] * out_deg[src[e]]^-1/2
//
// Round 24: REVERT to R22 (best, 120.6). R23 (EPB 1792, 2 blocks/CU)
//  REGRESSED to 126.3: the 1024-wide scan + ~21 barriers is a fixed
//  per-block cost, so doubling block count doubled aggregate scan work, and
//  halved per-block load parallelism; occupancy lever confirmed exhausted.
//  Final config: partition EPB=3584 (224 blocks, 1024 thr, int4 loads,
//  LDS-bucketed writeout), bincnt PART_SHIFT=7 (391 blocks, 2/CU), gather
//  wave-per-node readlane (random-line port floor).
//  Roofline accounting: fill ~46 (harness, in-window) + gather ~44
//  (2.4M random 64B lines @ ~53 G-lines/s; cache-residency falsified R17)
//  + partition ~11 + bincnt ~12 + memset/gaps ~7 ~= 120.

#define D_FEAT 96
#define CAP 64
#define PART_SHIFT 7
#define PNODES 128          // nodes per partition (1 << PART_SHIFT)
#define NP_MAX 512
#define EPB 3584            // 800k edges -> 224 blocks (<= 256 CUs, no tail)
#define EREG 4
#define VTHREADS 896        // EPB / 4: threads doing vectorized load/place
#define PTHREADS 1024
#define OVF_CAP 8192

__device__ __forceinline__ unsigned short f2bf_rne(float f) {
    unsigned u = __float_as_uint(f);
    unsigned r = (u >> 16) & 1u;
    u += 0x7fffu + r;
    return (unsigned short)(u >> 16);
}

// ------ pass 1: dual-side multisplit partition, LDS-bucketed writeout ------

__global__ __launch_bounds__(PTHREADS) void partition_kernel(
        const int* __restrict__ src, const int* __restrict__ dst,
        int n_edges, int np, int stride,
        int* __restrict__ pcur_d, int* __restrict__ pcur_s,
        unsigned* __restrict__ pbuf_d, unsigned short* __restrict__ pbuf_s,
        int* __restrict__ ctr,            // [0]=ovf_n [1]=povf_n [2]=sovf_n
        int* __restrict__ povf_d, int* __restrict__ sovf_d) {
    __shared__ int hist[2 * NP_MAX];          // [0,512): dst  [512,1024): src
    __shared__ int sdx[2 * NP_MAX];           // exclusive scan (src 0-based)
    __shared__ int ocur[2 * NP_MAX];          // placement counters
    __shared__ int gbase[2 * NP_MAX];         // reserved global bases
    __shared__ unsigned bufd[EPB];            // 14336 B: dst-side packed edges
    __shared__ unsigned short bufs[EPB];      // 7168 B: src-side ids
    const int t = threadIdx.x;
    const int base = blockIdx.x * EPB;
    const int eend = min(n_edges, base + EPB);
    const int nval = eend - base;
    const bool full = (base + EPB <= n_edges);

    hist[t] = 0; ocur[t] = 0;
    __syncthreads();

    unsigned v[EREG];
    if (full) {
        // vectorized: threads t < 896 handle edges base+4t .. base+4t+3
        if (t < VTHREADS) {
            const int4 s4 = *(const int4*)(src + base + (t << 2));
            const int4 d4 = *(const int4*)(dst + base + (t << 2));
            v[0] = (unsigned)d4.x | ((unsigned)s4.x << 16);
            v[1] = (unsigned)d4.y | ((unsigned)s4.y << 16);
            v[2] = (unsigned)d4.z | ((unsigned)s4.z << 16);
            v[3] = (unsigned)d4.w | ((unsigned)s4.w << 16);
            #pragma unroll
            for (int k = 0; k < EREG; ++k) {
                atomicAdd(&hist[(v[k] & 0xffffu) >> PART_SHIFT], 1);
                atomicAdd(&hist[NP_MAX + (v[k] >> (16 + PART_SHIFT))], 1);
            }
        }
    } else {
        #pragma unroll
        for (int k = 0; k < EREG; ++k) {
            int i = base + t + (k << 10);
            if (i < eend) {
                int s = src[i], d = dst[i];
                unsigned pv = (unsigned)d | ((unsigned)s << 16);
                v[k] = pv;
                atomicAdd(&hist[d >> PART_SHIFT], 1);
                atomicAdd(&hist[NP_MAX + (s >> PART_SHIFT)], 1);
            }
        }
    }
    __syncthreads();

    // inclusive Hillis-Steele scan over the 1024-entry concat histogram
    sdx[t] = hist[t];
    __syncthreads();
    for (int off = 1; off < 2 * NP_MAX; off <<= 1) {
        int a = sdx[t];
        int b = (t >= off) ? sdx[t - off] : 0;
        __syncthreads();
        sdx[t] = a + b;
        __syncthreads();
    }
    // convert to exclusive; re-base src half to 0
    {
        int incl = sdx[t];
        int td = sdx[NP_MAX - 1];           // total dst entries (= nval)
        __syncthreads();
        sdx[t] = incl - hist[t] - (t >= NP_MAX ? td : 0);
        __syncthreads();
    }

    // reserve global ranges (one atomic per non-empty (block, partition))
    {
        int c = hist[t];
        if (t < NP_MAX) gbase[t] = c ? atomicAdd(&pcur_d[t], c) : 0;
        else            gbase[t] = c ? atomicAdd(&pcur_s[t - NP_MAX], c) : 0;
    }

    // place edges into LDS buckets
    if (full) {
        if (t < VTHREADS) {
            #pragma unroll
            for (int k = 0; k < EREG; ++k) {
                unsigned pv = v[k];
                int pd = (int)((pv & 0xffffu) >> PART_SHIFT);
                int sl = sdx[pd] + atomicAdd(&ocur[pd], 1);
                bufd[sl] = pv;
                int ps = (int)(pv >> (16 + PART_SHIFT));
                int sl2 = sdx[NP_MAX + ps] + atomicAdd(&ocur[NP_MAX + ps], 1);
                bufs[sl2] = (unsigned short)(pv >> 16);
            }
        }
    } else {
        #pragma unroll
        for (int k = 0; k < EREG; ++k) {
            int i = base + t + (k << 10);
            if (i < eend) {
                unsigned pv = v[k];
                int pd = (int)((pv & 0xffffu) >> PART_SHIFT);
                int sl = sdx[pd] + atomicAdd(&ocur[pd], 1);
                bufd[sl] = pv;
                int ps = (int)(pv >> (16 + PART_SHIFT));
                int sl2 = sdx[NP_MAX + ps] + atomicAdd(&ocur[NP_MAX + ps], 1);
                bufs[sl2] = (unsigned short)(pv >> 16);
            }
        }
    }
    __syncthreads();

    // linear writeout: consecutive slots -> consecutive global addresses
    for (int i = t; i < nval; i += PTHREADS) {
        unsigned pv = bufd[i];
        int p = (int)((pv & 0xffffu) >> PART_SHIFT);
        int j = gbase[p] + (i - sdx[p]);
        if (j < stride) pbuf_d[(size_t)p * stride + j] = pv;
        else { int k2 = atomicAdd(&ctr[1], 1); if (k2 < OVF_CAP) povf_d[k2] = (int)pv; }
    }
    for (int i = t; i < nval; i += PTHREADS) {
        int s = (int)bufs[i];
        int p = s >> PART_SHIFT;
        int j = gbase[NP_MAX + p] + (i - sdx[NP_MAX + p]);
        if (j < stride) pbuf_s[(size_t)p * stride + j] = (unsigned short)s;
        else { int k3 = atomicAdd(&ctr[2], 1); if (k3 < OVF_CAP) sovf_d[k3] = s; }
    }
}

// ---- pass 2: bin dst + count src + integrate povf/sovf + convert (fused) ----

__global__ __launch_bounds__(PTHREADS) void bincnt_kernel(
        const unsigned* __restrict__ pbuf_d, const int* __restrict__ pcur_d,
        const unsigned short* __restrict__ pbuf_s, const int* __restrict__ pcur_s,
        int stride, int n_nodes,
        const float* __restrict__ x, unsigned* __restrict__ xs,
        int* __restrict__ cursor, int* __restrict__ out_cnt,
        unsigned short* __restrict__ slots,
        int* __restrict__ ctr,
        const int* __restrict__ povf_d, const int* __restrict__ sovf_d,
        int* __restrict__ ovf_d) {
    __shared__ unsigned short lslots[PNODES * CAP];   // 16 KB
    __shared__ int lcnt[PNODES];
    __shared__ int lout[PNODES];
    const int b = blockIdx.x;
    const int nbase = b << PART_SHIFT;
    const int nloc = min(PNODES, n_nodes - nbase);

    for (int i = threadIdx.x; i < PNODES; i += PTHREADS) { lcnt[i] = 0; lout[i] = 0; }
    __syncthreads();

    // dst side: bin into slots
    int n = pcur_d[b]; if (n > stride) n = stride;
    for (int i = threadIdx.x; i < n; i += PTHREADS) {
        unsigned pv = pbuf_d[(size_t)b * stride + i];
        int dl = (int)(pv & (unsigned)(PNODES - 1));   // d - nbase (aligned)
        int s  = (int)(pv >> 16);
        int pos = atomicAdd(&lcnt[dl], 1);
        if (pos < CAP) lslots[dl * CAP + pos] = (unsigned short)s;
        else { int k = atomicAdd(&ctr[0], 1); if (k < OVF_CAP) ovf_d[k] = (int)pv; }
    }
    // src side: histogram out-degree
    int n2 = pcur_s[b]; if (n2 > stride) n2 = stride;
    for (int i = threadIdx.x; i < n2; i += PTHREADS) {
        int s = (int)pbuf_s[(size_t)b * stride + i];
        atomicAdd(&lout[s & (PNODES - 1)], 1);
    }
    // integrate partition-buffer overflow entries for THIS node range
    // (ctr[1]/ctr[2] are normally 0 -> these loops never run)
    int npv = ctr[1];
    if (npv > 0) {
        if (npv > OVF_CAP) npv = OVF_CAP;
        for (int i = threadIdx.x; i < npv; i += PTHREADS) {
            unsigned pv = (unsigned)povf_d[i];
            int d = (int)(pv & 0xffffu);
            if ((d >> PART_SHIFT) == b) {
                int dl = d & (PNODES - 1);
                int pos = atomicAdd(&lcnt[dl], 1);
                if (pos < CAP) lslots[dl * CAP + pos] = (unsigned short)(pv >> 16);
                else { int k = atomicAdd(&ctr[0], 1); if (k < OVF_CAP) ovf_d[k] = (int)pv; }
            }
        }
    }
    int nsv = ctr[2];
    if (nsv > 0) {
        if (nsv > OVF_CAP) nsv = OVF_CAP;
        for (int i = threadIdx.x; i < nsv; i += PTHREADS) {
            int s = sovf_d[i];
            if ((s >> PART_SHIFT) == b) atomicAdd(&lout[s & (PNODES - 1)], 1);
        }
    }
    __syncthreads();

    for (int i = threadIdx.x; i < nloc; i += PTHREADS) {
        cursor[nbase + i]  = lcnt[i];
        out_cnt[nbase + i] = lout[i];
    }
    // slot tile write-out (coalesced)
    const unsigned* ls = (const unsigned*)lslots;
    unsigned* gs = (unsigned*)slots + (size_t)nbase * (CAP / 2);
    const int ncopy = nloc * (CAP / 2);
    for (int i = threadIdx.x; i < ncopy; i += PTHREADS) gs[i] = ls[i];

    // convert this block's x rows -> pre-scaled bf16 xs (float4 granular)
    const int ntot = nloc * 24;                 // 24 float4 per 96-feat row
    for (int i = threadIdx.x; i < ntot; i += PTHREADS) {
        int nd = i / 24;
        int j  = i - nd * 24;
        int c  = lout[nd];
        float w = rsqrtf((float)(c < 1 ? 1 : c));
        float4 vv = ((const float4*)(x + (size_t)(nbase + nd) * D_FEAT))[j];
        unsigned lo0 = f2bf_rne(vv.x * w), hi0 = f2bf_rne(vv.y * w);
        unsigned lo1 = f2bf_rne(vv.z * w), hi1 = f2bf_rne(vv.w * w);
        uint2 o;
        o.x = lo0 | (hi0 << 16);
        o.y = lo1 | (hi1 << 16);
        ((uint2*)(xs + (size_t)(nbase + nd) * 48))[j] = o;
    }
}

// ---------------- gather: wave per node, 16-deep unrolled, self-serve ovf ----

__global__ __launch_bounds__(256) void gather_kernel(
        const unsigned* __restrict__ xs,
        const unsigned short* __restrict__ slots,
        const int* __restrict__ cursor,
        const float* __restrict__ x,
        const int* __restrict__ out_cnt,
        const int* __restrict__ ctr,
        const int* __restrict__ ovf_d,
        float* __restrict__ out, int n_nodes) {
    int wid  = threadIdx.x >> 6;
    int lane = threadIdx.x & 63;
    int node = __builtin_amdgcn_readfirstlane(blockIdx.x * 4 + wid);
    if (node >= n_nodes) return;

    int cnt_all = __builtin_amdgcn_readfirstlane(cursor[node]);
    int cnt = cnt_all < CAP ? cnt_all : CAP;

    float accx = 0.f, accy = 0.f;
    const bool act = lane < 48;        // 48 lanes x (2 bf16) = 96 features

    if (cnt > 0) {
        int idx  = lane < cnt ? lane : cnt - 1;
        int sval = (int)slots[node * CAP + idx];   // lane l holds slot l's src id

        int e = 0;
        for (; e + 16 <= cnt; e += 16) {
            if (act) {
                unsigned u[16];
                #pragma unroll
                for (int k = 0; k < 16; ++k) {
                    int s = __builtin_amdgcn_readlane(sval, e + k);
                    u[k] = xs[s * 48 + lane];
                }
                #pragma unroll
                for (int k = 0; k < 16; ++k) {
                    accx += __uint_as_float(u[k] << 16);
                    accy += __uint_as_float(u[k] & 0xffff0000u);
                }
            }
        }
        for (; e + 4 <= cnt; e += 4) {
            if (act) {
                unsigned u[4];
                #pragma unroll
                for (int k = 0; k < 4; ++k) {
                    int s = __builtin_amdgcn_readlane(sval, e + k);
                    u[k] = xs[s * 48 + lane];
                }
                #pragma unroll
                for (int k = 0; k < 4; ++k) {
                    accx += __uint_as_float(u[k] << 16);
                    accy += __uint_as_float(u[k] & 0xffff0000u);
                }
            }
        }
        for (; e < cnt; ++e) {
            if (act) {
                int s = __builtin_amdgcn_readlane(sval, e);
                unsigned u0 = xs[s * 48 + lane];
                accx += __uint_as_float(u0 << 16);
                accy += __uint_as_float(u0 & 0xffff0000u);
            }
        }
    }

    // self-service overflow: only nodes with in-degree > CAP (normally none).
    if (cnt_all > CAP) {
        int novf = __builtin_amdgcn_readfirstlane(ctr[0]);
        if (novf > OVF_CAP) novf = OVF_CAP;
        for (int k = 0; k < novf; ++k) {
            unsigned pv = (unsigned)ovf_d[k];
            if ((int)(pv & 0xffffu) == node) {
                int s = (int)(pv >> 16);
                int c = out_cnt[s];
                float w = rsqrtf((float)(c < 1 ? 1 : c));
                if (act) {
                    accx += w * x[(size_t)s * D_FEAT + lane * 2];
                    accy += w * x[(size_t)s * D_FEAT + lane * 2 + 1];
                }
            }
        }
    }

    float sc = rsqrtf((float)(cnt_all < 1 ? 1 : cnt_all));
    if (act) {
        float* op = out + (size_t)node * D_FEAT + lane * 2;
        op[0] = accx * sc;
        op[1] = accy * sc;
    }
}

// ---------------- fallback (round-1 atomic scatter, any size) ----------------

__global__ void degree_kernel(const int* __restrict__ src,
                              const int* __restrict__ dst,
                              int* __restrict__ out_cnt,
                              int* __restrict__ in_cnt, int n_edges) {
    int i = blockIdx.x * blockDim.x + threadIdx.x;
    if (i < n_edges) {
        atomicAdd(&out_cnt[src[i]], 1);
        atomicAdd(&in_cnt[dst[i]], 1);
    }
}

__global__ void scale_kernel(float* __restrict__ osc, float* __restrict__ isc, int n) {
    int i = blockIdx.x * blockDim.x + threadIdx.x;
    if (i < n) {
        int c0 = ((const int*)osc)[i];
        int c1 = ((const int*)isc)[i];
        osc[i] = rsqrtf((float)(c0 < 1 ? 1 : c0));
        isc[i] = rsqrtf((float)(c1 < 1 ? 1 : c1));
    }
}

__global__ void scatter_kernel(const float* __restrict__ x,
                               const int* __restrict__ src,
                               const int* __restrict__ dst,
                               const float* __restrict__ osc,
                               const float* __restrict__ isc,
                               float* __restrict__ out, int n_edges) {
    int idx = blockIdx.x * blockDim.x + threadIdx.x;
    int e = idx / 24, c = idx % 24;
    if (e >= n_edges) return;
    int s = src[e], d = dst[e];
    float w = osc[s] * isc[d];
    const float4 v = *(const float4*)(x + (size_t)s * D_FEAT + c * 4);
    float* o = out + (size_t)d * D_FEAT + c * 4;
    unsafeAtomicAdd(o + 0, v.x * w);
    unsafeAtomicAdd(o + 1, v.y * w);
    unsafeAtomicAdd(o + 2, v.z * w);
    unsafeAtomicAdd(o + 3, v.w * w);
}

// ---------------- launcher ----------------

extern "C" void kernel_launch(void* const* d_in, const int* in_sizes, int n_in,
                              void* d_out, int out_size, void* d_ws, size_t ws_size,
                              hipStream_t stream) {
    const float* x  = (const float*)d_in[0];
    const int* src  = (const int*)d_in[1];
    const int* dst  = (const int*)d_in[2];
    float* out      = (float*)d_out;

    const int n_edges = in_sizes[1];
    const int n_nodes = in_sizes[0] / D_FEAT;

    const int np = (n_nodes + PNODES - 1) / PNODES;
    const int avg = n_edges / (np > 0 ? np : 1);
    const int stride = avg + avg / 4 + 1024;
    const int pblocks = (n_edges + EPB - 1) / EPB;

    const size_t pbuf_words  = (size_t)np * stride;          // dst buffer (uint)
    const size_t pbufs_words = (pbuf_words + 1) / 2;         // src buffer (ushort)

    // ws layout (int32 units). First 2048 ints zeroed each call:
    int* pcur_d  = (int*)d_ws;            // 512
    int* pcur_s  = pcur_d + 512;          // 512
    int* ctr     = pcur_d + 1024;         // 3 (pad to 2048)
    int* ovf_d   = pcur_d + 2048;         // OVF_CAP (packed v)
    int* povf_d  = ovf_d + OVF_CAP;       // OVF_CAP
    int* sovf_d  = povf_d + OVF_CAP;      // OVF_CAP
    int* out_cnt = sovf_d + OVF_CAP;      // 65536
    int* cursor  = out_cnt + 65536;       // 65536
    unsigned* pbuf_dst = (unsigned*)(cursor + 65536);
    unsigned short* pbuf_src = (unsigned short*)(pbuf_dst + pbuf_words);
    unsigned* xs = pbuf_dst + pbuf_words + pbufs_words;
    unsigned short* slots = (unsigned short*)(xs + (size_t)n_nodes * 48);

    const size_t needed = ((size_t)2048 + 3 * OVF_CAP + 2 * 65536 + pbuf_words +
                           pbufs_words + (size_t)n_nodes * 48 +
                           (size_t)n_nodes * (CAP / 2)) * 4;

    if (ws_size >= needed && n_nodes <= 65536 && np <= NP_MAX && pblocks <= 256) {
        // zero pcur_d, pcur_s, ctr
        (void)hipMemsetAsync(d_ws, 0, 2048 * sizeof(int), stream);

        partition_kernel<<<pblocks, PTHREADS, 0, stream>>>(
            src, dst, n_edges, np, stride, pcur_d, pcur_s,
            pbuf_dst, pbuf_src, ctr, povf_d, sovf_d);

        bincnt_kernel<<<np, PTHREADS, 0, stream>>>(
            pbuf_dst, pcur_d, pbuf_src, pcur_s, stride, n_nodes,
            x, xs, cursor, out_cnt, slots, ctr, povf_d, sovf_d, ovf_d);

        gather_kernel<<<(n_nodes + 3) / 4, 256, 0, stream>>>(
            xs, slots, cursor, x, out_cnt, ctr, ovf_d, out, n_nodes);
    } else {
        // fallback: atomic scatter (round-1 path, any size)
        float* osc = (float*)d_ws;
        float* isc = osc + 65536;
        (void)hipMemsetAsync(d_ws, 0, 2 * 65536 * sizeof(int), stream);
        (void)hipMemsetAsync(d_out, 0, (size_t)out_size * sizeof(float), stream);
        degree_kernel<<<(n_edges + 255) / 256, 256, 0, stream>>>(
            src, dst, (int*)osc, (int*)isc, n_edges);
        scale_kernel<<<(n_nodes + 255) / 256, 256, 0, stream>>>(osc, isc, n_nodes);
        const int total = n_edges * 24;
        scatter_kernel<<<(total + 255) / 256, 256, 0, stream>>>(
            x, src, dst, osc, isc, out, n_edges);
    }
}